// Round 2
// baseline (552.193 us; speedup 1.0000x reference)
//
#include <hip/hip_runtime.h>

#define T_TOK 4096
#define H_DIM 2048
#define I_DIM 1408
#define E_NUM 8
#define TOPK  2
#define NPAIR (T_TOK*TOPK)
#define BM 128
#define BK 32

typedef float f32x4 __attribute__((ext_vector_type(4)));
typedef short s16x8 __attribute__((ext_vector_type(8)));

static __device__ __forceinline__ short f2bf(float f) {
  union { float f; unsigned u; } c; c.f = f;
  unsigned r = c.u + 0x7FFFu + ((c.u >> 16) & 1u);
  return (short)(r >> 16);
}
static __device__ __forceinline__ int swz(int r) { return (r & 3) ^ ((r >> 2) & 3); }

// ---------------- pair sort + tile descriptors ----------------
__global__ __launch_bounds__(256) void moe_build(
    const int* __restrict__ idx, const float* __restrict__ wts,
    int* __restrict__ tok_s, float* __restrict__ wt_s,
    int* __restrict__ tile_e, int* __restrict__ tile_r0,
    int* __restrict__ tile_r1, int* __restrict__ ntiles) {
  __shared__ int cnt[E_NUM], cur[E_NUM];
  int tid = threadIdx.x;
  if (tid < E_NUM) cnt[tid] = 0;
  __syncthreads();
  for (int p = tid; p < NPAIR; p += 256) atomicAdd(&cnt[idx[p] & 7], 1);
  __syncthreads();
  if (tid == 0) {
    int o = 0, nt = 0;
    for (int e = 0; e < E_NUM; e++) {
      cur[e] = o;
      int c = cnt[e];
      for (int m0 = 0; m0 < c; m0 += BM) {
        tile_e[nt] = e;
        tile_r0[nt] = o + m0;
        tile_r1[nt] = o + ((m0 + BM < c) ? (m0 + BM) : c);
        nt++;
      }
      o += c;
    }
    *ntiles = nt;
  }
  __syncthreads();
  for (int p = tid; p < NPAIR; p += 256) {
    int e = idx[p] & 7;
    int pos = atomicAdd(&cur[e], 1);
    tok_s[pos] = p >> 1;      // token id (pairs are [T][K] row-major, K=2)
    wt_s[pos]  = wts[p];
  }
}

// ---------------- GEMM1: act = silu(X@Wg) * (X@Wu), bf16 out ----------------
__global__ __launch_bounds__(256) void moe_gemm1(
    const float* __restrict__ hidden, const float* __restrict__ Wg,
    const float* __restrict__ Wu, const int* __restrict__ tok_s,
    const int* __restrict__ tile_e, const int* __restrict__ tile_r0,
    const int* __restrict__ tile_r1, const int* __restrict__ ntiles,
    short* __restrict__ act) {
  int bt = blockIdx.x;
  if (bt >= *ntiles) return;
  int e = tile_e[bt], r0 = tile_r0[bt], r1 = tile_r1[bt];
  int n0 = blockIdx.y * 64;
  const float* wg = Wg + (size_t)e * ((size_t)H_DIM * I_DIM);
  const float* wu = Wu + (size_t)e * ((size_t)H_DIM * I_DIM);

  __shared__ short As[BM * BK];
  __shared__ short Bg[64 * BK];
  __shared__ short Bu[64 * BK];

  int tid = threadIdx.x;
  // A staging: 2 threads per row, each 16 floats
  int ar = tid >> 1, ah = tid & 1;
  int ap = r0 + ar; if (ap > NPAIR - 1) ap = NPAIR - 1;
  int atok = tok_s[ap];
  const float* asrc = hidden + (size_t)atok * H_DIM + ah * 16;
  int asw = swz(ar);
  s16x8* aw0 = (s16x8*)&As[ar * BK + (((ah * 2 + 0) ^ asw) << 3)];
  s16x8* aw1 = (s16x8*)&As[ar * BK + (((ah * 2 + 1) ^ asw) << 3)];
  // B staging: thread -> (n, k-group of 8); transposed to LDS [n][k]
  int bn = tid & 63, bkg = tid >> 6;
  const float* bg0 = wg + (size_t)(bkg * 8) * I_DIM + n0 + bn;
  const float* bu0 = wu + (size_t)(bkg * 8) * I_DIM + n0 + bn;
  int bso = bn * BK + ((bkg ^ swz(bn)) << 3);
  s16x8* bwg = (s16x8*)&Bg[bso];
  s16x8* bwu = (s16x8*)&Bu[bso];

  int lane = tid & 63, wv = tid >> 6;
  int wm = wv >> 1, wn = wv & 1;
  int lrow = lane & 15, lk = lane >> 4;

  f32x4 accg[4][2], accu[4][2];
  #pragma unroll
  for (int i = 0; i < 4; i++)
    #pragma unroll
    for (int j = 0; j < 2; j++) { accg[i][j] = 0; accu[i][j] = 0; }

  for (int k0 = 0; k0 < H_DIM; k0 += BK) {
    const float4* a = (const float4*)(asrc + k0);
    float4 f0 = a[0], f1 = a[1], f2 = a[2], f3 = a[3];
    float vgv[8], vuv[8];
    const float* pg = bg0 + (size_t)k0 * I_DIM;
    const float* pu = bu0 + (size_t)k0 * I_DIM;
    #pragma unroll
    for (int j = 0; j < 8; j++) { vgv[j] = pg[(size_t)j * I_DIM]; vuv[j] = pu[(size_t)j * I_DIM]; }
    __syncthreads();
    s16x8 p0, p1, qg, qu;
    p0[0]=f2bf(f0.x); p0[1]=f2bf(f0.y); p0[2]=f2bf(f0.z); p0[3]=f2bf(f0.w);
    p0[4]=f2bf(f1.x); p0[5]=f2bf(f1.y); p0[6]=f2bf(f1.z); p0[7]=f2bf(f1.w);
    p1[0]=f2bf(f2.x); p1[1]=f2bf(f2.y); p1[2]=f2bf(f2.z); p1[3]=f2bf(f2.w);
    p1[4]=f2bf(f3.x); p1[5]=f2bf(f3.y); p1[6]=f2bf(f3.z); p1[7]=f2bf(f3.w);
    #pragma unroll
    for (int j = 0; j < 8; j++) { qg[j] = f2bf(vgv[j]); qu[j] = f2bf(vuv[j]); }
    *aw0 = p0; *aw1 = p1; *bwg = qg; *bwu = qu;
    __syncthreads();
    s16x8 af[4], bfg[2], bfu[2];
    #pragma unroll
    for (int mf = 0; mf < 4; mf++) {
      int rr = wm * 64 + mf * 16 + lrow;
      af[mf] = *(const s16x8*)&As[rr * BK + ((lk ^ swz(rr)) << 3)];
    }
    #pragma unroll
    for (int nf = 0; nf < 2; nf++) {
      int rn = wn * 32 + nf * 16 + lrow;
      int ob = rn * BK + ((lk ^ swz(rn)) << 3);
      bfg[nf] = *(const s16x8*)&Bg[ob];
      bfu[nf] = *(const s16x8*)&Bu[ob];
    }
    #pragma unroll
    for (int mf = 0; mf < 4; mf++)
      #pragma unroll
      for (int nf = 0; nf < 2; nf++) {
        accg[mf][nf] = __builtin_amdgcn_mfma_f32_16x16x32_bf16(af[mf], bfg[nf], accg[mf][nf], 0, 0, 0);
        accu[mf][nf] = __builtin_amdgcn_mfma_f32_16x16x32_bf16(af[mf], bfu[nf], accu[mf][nf], 0, 0, 0);
      }
  }
  // epilogue: silu(g)*u -> bf16 act
  #pragma unroll
  for (int mf = 0; mf < 4; mf++) {
    int rb = r0 + wm * 64 + mf * 16 + (lk << 2);
    #pragma unroll
    for (int nf = 0; nf < 2; nf++) {
      int col = n0 + wn * 32 + nf * 16 + lrow;
      #pragma unroll
      for (int j = 0; j < 4; j++) {
        int p = rb + j;
        if (p < r1) {
          float g = accg[mf][nf][j], u = accu[mf][nf][j];
          float s = g / (1.f + __expf(-g)) * u;
          act[p * I_DIM + col] = f2bf(s);
        }
      }
    }
  }
}

// ---------------- GEMM2: out[tok] += wt * (act @ Wd) ----------------
__global__ __launch_bounds__(256) void moe_gemm2(
    const short* __restrict__ act, const float* __restrict__ Wd,
    const int* __restrict__ tok_s, const float* __restrict__ wt_s,
    const int* __restrict__ tile_e, const int* __restrict__ tile_r0,
    const int* __restrict__ tile_r1, const int* __restrict__ ntiles,
    float* __restrict__ out) {
  int bt = blockIdx.x;
  if (bt >= *ntiles) return;
  int e = tile_e[bt], r0 = tile_r0[bt], r1 = tile_r1[bt];
  int n0 = blockIdx.y * 64;
  const float* wd = Wd + (size_t)e * ((size_t)I_DIM * H_DIM);

  __shared__ short As[BM * BK];
  __shared__ short Bd[64 * BK];

  int tid = threadIdx.x;
  int ar = tid >> 1, ah = tid & 1;
  int ap = r0 + ar; if (ap > NPAIR - 1) ap = NPAIR - 1;
  const short* asrc = act + (size_t)ap * I_DIM + ah * 16;
  int asw = swz(ar);
  s16x8* aw0 = (s16x8*)&As[ar * BK + (((ah * 2 + 0) ^ asw) << 3)];
  s16x8* aw1 = (s16x8*)&As[ar * BK + (((ah * 2 + 1) ^ asw) << 3)];

  int bn = tid & 63, bkg = tid >> 6;
  const float* bd0 = wd + (size_t)(bkg * 8) * H_DIM + n0 + bn;
  s16x8* bwd = (s16x8*)&Bd[bn * BK + ((bkg ^ swz(bn)) << 3)];

  int lane = tid & 63, wv = tid >> 6;
  int wm = wv >> 1, wn = wv & 1;
  int lrow = lane & 15, lk = lane >> 4;

  f32x4 acc[4][2];
  #pragma unroll
  for (int i = 0; i < 4; i++)
    #pragma unroll
    for (int j = 0; j < 2; j++) acc[i][j] = 0;

  for (int k0 = 0; k0 < I_DIM; k0 += BK) {
    const s16x8* a = (const s16x8*)(asrc + k0);
    s16x8 v0 = a[0], v1 = a[1];
    float vd[8];
    const float* pd = bd0 + (size_t)k0 * H_DIM;
    #pragma unroll
    for (int j = 0; j < 8; j++) vd[j] = pd[(size_t)j * H_DIM];
    __syncthreads();
    s16x8 qd;
    #pragma unroll
    for (int j = 0; j < 8; j++) qd[j] = f2bf(vd[j]);
    *aw0 = v0; *aw1 = v1; *bwd = qd;
    __syncthreads();
    s16x8 af[4], bf[2];
    #pragma unroll
    for (int mf = 0; mf < 4; mf++) {
      int rr = wm * 64 + mf * 16 + lrow;
      af[mf] = *(const s16x8*)&As[rr * BK + ((lk ^ swz(rr)) << 3)];
    }
    #pragma unroll
    for (int nf = 0; nf < 2; nf++) {
      int rn = wn * 32 + nf * 16 + lrow;
      bf[nf] = *(const s16x8*)&Bd[rn * BK + ((lk ^ swz(rn)) << 3)];
    }
    #pragma unroll
    for (int mf = 0; mf < 4; mf++)
      #pragma unroll
      for (int nf = 0; nf < 2; nf++)
        acc[mf][nf] = __builtin_amdgcn_mfma_f32_16x16x32_bf16(af[mf], bf[nf], acc[mf][nf], 0, 0, 0);
  }
  #pragma unroll
  for (int mf = 0; mf < 4; mf++) {
    int rb = r0 + wm * 64 + mf * 16 + (lk << 2);
    #pragma unroll
    for (int nf = 0; nf < 2; nf++) {
      int col = n0 + wn * 32 + nf * 16 + lrow;
      #pragma unroll
      for (int j = 0; j < 4; j++) {
        int p = rb + j;
        if (p < r1) {
          atomicAdd(&out[(size_t)tok_s[p] * H_DIM + col], wt_s[p] * acc[mf][nf][j]);
        }
      }
    }
  }
}

extern "C" void kernel_launch(void* const* d_in, const int* in_sizes, int n_in,
                              void* d_out, int out_size, void* d_ws, size_t ws_size,
                              hipStream_t stream) {
  const float* hidden = (const float*)d_in[0];
  const int*   idx    = (const int*)d_in[1];    // int64 in reference -> int32 in harness
  const float* wts    = (const float*)d_in[2];
  const float* Wg     = (const float*)d_in[3];
  const float* Wu     = (const float*)d_in[4];
  const float* Wd     = (const float*)d_in[5];
  float* out = (float*)d_out;

  char* ws = (char*)d_ws;
  int*   tok_s   = (int*)(ws);             // 8192 * 4
  float* wt_s    = (float*)(ws + 32768);   // 8192 * 4
  int*   tile_e  = (int*)(ws + 65536);     // 128 * 4
  int*   tile_r0 = (int*)(ws + 66048);
  int*   tile_r1 = (int*)(ws + 66560);
  int*   ntiles  = (int*)(ws + 67072);
  short* act     = (short*)(ws + 131072);  // 8192 * 1408 * 2 = 23068672 B

  moe_build<<<1, 256, 0, stream>>>(idx, wts, tok_s, wt_s, tile_e, tile_r0, tile_r1, ntiles);
  hipMemsetAsync(d_out, 0, (size_t)T_TOK * H_DIM * sizeof(float), stream);
  moe_gemm1<<<dim3(72, I_DIM / 64), 256, 0, stream>>>(hidden, Wg, Wu, tok_s,
      tile_e, tile_r0, tile_r1, ntiles, act);
  moe_gemm2<<<dim3(72, H_DIM / 64), 256, 0, stream>>>(act, Wd, tok_s, wt_s,
      tile_e, tile_r0, tile_r1, ntiles, out);
}

// Round 3
// 445.201 us; speedup vs baseline: 1.2403x; 1.2403x over previous
//
#include <hip/hip_runtime.h>

#define T_TOK 4096
#define H_DIM 2048
#define I_DIM 1408
#define E_NUM 8
#define NPAIR 8192
#define BM 128
#define BK 64

typedef float f32x4 __attribute__((ext_vector_type(4)));
typedef short s16x8 __attribute__((ext_vector_type(8)));

static __device__ __forceinline__ short f2bf(float f) {
  union { float f; unsigned u; } c; c.f = f;
  unsigned r = c.u + 0x7FFFu + ((c.u >> 16) & 1u);
  return (short)(r >> 16);
}
static __device__ __forceinline__ int swz32(int r) { return (r & 3) ^ ((r >> 2) & 3); }

// global -> LDS direct, 16B per lane. LDS dest = wave-uniform base + lane*16.
#define GLD16(g, l) __builtin_amdgcn_global_load_lds( \
    (const __attribute__((address_space(1))) void*)(g), \
    (__attribute__((address_space(3))) void*)(l), 16, 0, 0)

// ---------------- pair sort + tile descriptors ----------------
__global__ __launch_bounds__(256) void moe_build(
    const int* __restrict__ idx, const float* __restrict__ wts,
    int* __restrict__ tok_s, float* __restrict__ wt_s,
    int* __restrict__ tile_e, int* __restrict__ tile_r0,
    int* __restrict__ tile_r1, int* __restrict__ ntiles) {
  __shared__ int cnt[E_NUM], cur[E_NUM];
  int tid = threadIdx.x;
  if (tid < E_NUM) cnt[tid] = 0;
  __syncthreads();
  for (int p = tid; p < NPAIR; p += 256) atomicAdd(&cnt[idx[p] & 7], 1);
  __syncthreads();
  if (tid == 0) {
    int o = 0, nt = 0;
    for (int e = 0; e < E_NUM; e++) {
      cur[e] = o;
      int c = cnt[e];
      for (int m0 = 0; m0 < c; m0 += BM) {
        tile_e[nt] = e;
        tile_r0[nt] = o + m0;
        tile_r1[nt] = o + ((m0 + BM < c) ? (m0 + BM) : c);
        nt++;
      }
      o += c;
    }
    *ntiles = nt;
  }
  __syncthreads();
  for (int p = tid; p < NPAIR; p += 256) {
    int e = idx[p] & 7;
    int pos = atomicAdd(&cur[e], 1);
    tok_s[pos] = p >> 1;
    wt_s[pos]  = wts[p];
  }
}

// ---------------- prepass: hidden fp32 -> bf16 ----------------
__global__ __launch_bounds__(256) void conv_hidden(
    const float* __restrict__ in, short* __restrict__ out) {
  size_t i = ((size_t)blockIdx.x * 256 + threadIdx.x) * 16;
  const f32x4* s = (const f32x4*)(in + i);
  f32x4 a = s[0], b = s[1], c = s[2], d = s[3];
  s16x8 v0, v1;
  v0[0]=f2bf(a[0]); v0[1]=f2bf(a[1]); v0[2]=f2bf(a[2]); v0[3]=f2bf(a[3]);
  v0[4]=f2bf(b[0]); v0[5]=f2bf(b[1]); v0[6]=f2bf(b[2]); v0[7]=f2bf(b[3]);
  v1[0]=f2bf(c[0]); v1[1]=f2bf(c[1]); v1[2]=f2bf(c[2]); v1[3]=f2bf(c[3]);
  v1[4]=f2bf(d[0]); v1[5]=f2bf(d[1]); v1[6]=f2bf(d[2]); v1[7]=f2bf(d[3]);
  *(s16x8*)(out + i) = v0;
  *(s16x8*)(out + i + 8) = v1;
}

// ---------------- prepass: [E][R][C] fp32 -> [E][C][R] bf16 ----------------
__global__ __launch_bounds__(256) void transpose_w(
    const float* __restrict__ in, short* __restrict__ out, int R, int C) {
  __shared__ short t[64][72];
  const float* src = in + (size_t)blockIdx.z * ((size_t)R * C);
  short* dst = out + (size_t)blockIdx.z * ((size_t)R * C);
  int r0 = blockIdx.y * 64, c0 = blockIdx.x * 64;
  int tid = threadIdx.x;
  int ir = tid >> 2, ic = (tid & 3) * 16;
  const f32x4* s = (const f32x4*)(src + (size_t)(r0 + ir) * C + c0 + ic);
  f32x4 a = s[0], b = s[1], c = s[2], d = s[3];
  short* w = &t[ir][ic];
  w[0]=f2bf(a[0]);  w[1]=f2bf(a[1]);  w[2]=f2bf(a[2]);  w[3]=f2bf(a[3]);
  w[4]=f2bf(b[0]);  w[5]=f2bf(b[1]);  w[6]=f2bf(b[2]);  w[7]=f2bf(b[3]);
  w[8]=f2bf(c[0]);  w[9]=f2bf(c[1]);  w[10]=f2bf(c[2]); w[11]=f2bf(c[3]);
  w[12]=f2bf(d[0]); w[13]=f2bf(d[1]); w[14]=f2bf(d[2]); w[15]=f2bf(d[3]);
  __syncthreads();
  int oc = tid >> 2, os = (tid & 3) * 16;
  s16x8 v0, v1;
  #pragma unroll
  for (int j = 0; j < 8; j++) { v0[j] = t[os + j][oc]; v1[j] = t[os + 8 + j][oc]; }
  short* o = dst + (size_t)(c0 + oc) * R + r0 + os;
  *(s16x8*)o = v0;
  *(s16x8*)(o + 8) = v1;
}

// ---------------- GEMM1: act = silu(X@Wg) * (X@Wu), all bf16 ----------------
// A: hb [T][H] bf16 gathered rows; B: Wgt/Wut [E][I][H] bf16 (K-contiguous rows)
__global__ __launch_bounds__(256) void moe_gemm1(
    const short* __restrict__ hb, const short* __restrict__ Wgt,
    const short* __restrict__ Wut, const int* __restrict__ tok_s,
    const int* __restrict__ tile_e, const int* __restrict__ tile_r0,
    const int* __restrict__ tile_r1, const int* __restrict__ ntiles,
    short* __restrict__ act) {
  __shared__ short As[BM * BK];     // [128][64], chunk-swizzled
  __shared__ short Bg[64 * BK];     // [64][64]
  __shared__ short Bu[64 * BK];
  int bt = blockIdx.x;
  if (bt >= *ntiles) return;
  int e = tile_e[bt], r0 = tile_r0[bt], r1 = tile_r1[bt];
  int n0 = blockIdx.y * 64;
  const short* wg = Wgt + (size_t)e * ((size_t)H_DIM * I_DIM);
  const short* wu = Wut + (size_t)e * ((size_t)H_DIM * I_DIM);

  int tid = threadIdx.x, lane = tid & 63, wv = tid >> 6;
  int l3 = lane >> 3;
  int k8 = (((lane & 7) ^ (l3 & 7)) << 3);   // inverse-swizzled source k-chunk

  const short* a_src[4]; short* a_dst[4];
  #pragma unroll
  for (int s = 0; s < 4; s++) {
    int row = wv * 32 + s * 8 + l3;
    int p = r0 + row; if (p > NPAIR - 1) p = NPAIR - 1;
    a_src[s] = hb + (size_t)tok_s[p] * H_DIM + k8;
    a_dst[s] = As + (wv * 32 + s * 8) * BK;
  }
  const short* g_src[2]; short* g_dst[2];
  const short* u_src[2]; short* u_dst[2];
  #pragma unroll
  for (int s = 0; s < 2; s++) {
    int n = wv * 16 + s * 8 + l3;
    g_src[s] = wg + (size_t)(n0 + n) * H_DIM + k8;
    u_src[s] = wu + (size_t)(n0 + n) * H_DIM + k8;
    g_dst[s] = Bg + (wv * 16 + s * 8) * BK;
    u_dst[s] = Bu + (wv * 16 + s * 8) * BK;
  }

  int wm = wv >> 1, wn = wv & 1;
  int lrow = lane & 15, lk = lane >> 4;

  f32x4 accg[4][2], accu[4][2];
  #pragma unroll
  for (int i = 0; i < 4; i++)
    #pragma unroll
    for (int j = 0; j < 2; j++) { accg[i][j] = 0; accu[i][j] = 0; }

  for (int k0 = 0; k0 < H_DIM; k0 += BK) {
    #pragma unroll
    for (int s = 0; s < 4; s++) GLD16(a_src[s] + k0, a_dst[s]);
    #pragma unroll
    for (int s = 0; s < 2; s++) { GLD16(g_src[s] + k0, g_dst[s]); GLD16(u_src[s] + k0, u_dst[s]); }
    __syncthreads();
    #pragma unroll
    for (int ks = 0; ks < 2; ks++) {
      s16x8 af[4], bgf[2], buf_[2];
      #pragma unroll
      for (int mf = 0; mf < 4; mf++) {
        int rr = wm * 64 + mf * 16 + lrow;
        af[mf] = *(const s16x8*)&As[rr * BK + ((((ks << 2) + lk) ^ (rr & 7)) << 3)];
      }
      #pragma unroll
      for (int nf = 0; nf < 2; nf++) {
        int rn = wn * 32 + nf * 16 + lrow;
        int o = rn * BK + ((((ks << 2) + lk) ^ (rn & 7)) << 3);
        bgf[nf] = *(const s16x8*)&Bg[o];
        buf_[nf] = *(const s16x8*)&Bu[o];
      }
      #pragma unroll
      for (int mf = 0; mf < 4; mf++)
        #pragma unroll
        for (int nf = 0; nf < 2; nf++) {
          accg[mf][nf] = __builtin_amdgcn_mfma_f32_16x16x32_bf16(af[mf], bgf[nf], accg[mf][nf], 0, 0, 0);
          accu[mf][nf] = __builtin_amdgcn_mfma_f32_16x16x32_bf16(af[mf], buf_[nf], accu[mf][nf], 0, 0, 0);
        }
    }
    __syncthreads();
  }
  #pragma unroll
  for (int mf = 0; mf < 4; mf++) {
    int rb = r0 + wm * 64 + mf * 16 + (lk << 2);
    #pragma unroll
    for (int nf = 0; nf < 2; nf++) {
      int col = n0 + wn * 32 + nf * 16 + lrow;
      #pragma unroll
      for (int j = 0; j < 4; j++) {
        int p = rb + j;
        if (p < r1) {
          float g = accg[mf][nf][j], u = accu[mf][nf][j];
          float s = g / (1.f + __expf(-g)) * u;
          act[p * I_DIM + col] = f2bf(s);
        }
      }
    }
  }
}

// ---------------- GEMM2: out[tok] += wt * (act @ Wd), bf16 MFMA ----------------
__global__ __launch_bounds__(256) void moe_gemm2(
    const short* __restrict__ act, const short* __restrict__ Wdt,
    const int* __restrict__ tok_s, const float* __restrict__ wt_s,
    const int* __restrict__ tile_e, const int* __restrict__ tile_r0,
    const int* __restrict__ tile_r1, const int* __restrict__ ntiles,
    float* __restrict__ out) {
  __shared__ short As[BM * BK];
  __shared__ short Bd[64 * BK];
  int bt = blockIdx.x;
  if (bt >= *ntiles) return;
  int e = tile_e[bt], r0 = tile_r0[bt], r1 = tile_r1[bt];
  int n0 = blockIdx.y * 64;
  const short* wd = Wdt + (size_t)e * ((size_t)H_DIM * I_DIM);

  int tid = threadIdx.x, lane = tid & 63, wv = tid >> 6;
  int l3 = lane >> 3;
  int k8 = (((lane & 7) ^ (l3 & 7)) << 3);

  const short* a_src[4]; short* a_dst[4];
  #pragma unroll
  for (int s = 0; s < 4; s++) {
    int row = wv * 32 + s * 8 + l3;
    int p = r0 + row; if (p > NPAIR - 1) p = NPAIR - 1;
    a_src[s] = act + (size_t)p * I_DIM + k8;
    a_dst[s] = As + (wv * 32 + s * 8) * BK;
  }
  const short* b_src[2]; short* b_dst[2];
  #pragma unroll
  for (int s = 0; s < 2; s++) {
    int n = wv * 16 + s * 8 + l3;
    b_src[s] = wd + (size_t)(n0 + n) * I_DIM + k8;
    b_dst[s] = Bd + (wv * 16 + s * 8) * BK;
  }

  int wm = wv >> 1, wn = wv & 1;
  int lrow = lane & 15, lk = lane >> 4;

  f32x4 acc[4][2];
  #pragma unroll
  for (int i = 0; i < 4; i++)
    #pragma unroll
    for (int j = 0; j < 2; j++) acc[i][j] = 0;

  for (int k0 = 0; k0 < I_DIM; k0 += BK) {
    #pragma unroll
    for (int s = 0; s < 4; s++) GLD16(a_src[s] + k0, a_dst[s]);
    #pragma unroll
    for (int s = 0; s < 2; s++) GLD16(b_src[s] + k0, b_dst[s]);
    __syncthreads();
    #pragma unroll
    for (int ks = 0; ks < 2; ks++) {
      s16x8 af[4], bf[2];
      #pragma unroll
      for (int mf = 0; mf < 4; mf++) {
        int rr = wm * 64 + mf * 16 + lrow;
        af[mf] = *(const s16x8*)&As[rr * BK + ((((ks << 2) + lk) ^ (rr & 7)) << 3)];
      }
      #pragma unroll
      for (int nf = 0; nf < 2; nf++) {
        int rn = wn * 32 + nf * 16 + lrow;
        bf[nf] = *(const s16x8*)&Bd[rn * BK + ((((ks << 2) + lk) ^ (rn & 7)) << 3)];
      }
      #pragma unroll
      for (int mf = 0; mf < 4; mf++)
        #pragma unroll
        for (int nf = 0; nf < 2; nf++)
          acc[mf][nf] = __builtin_amdgcn_mfma_f32_16x16x32_bf16(af[mf], bf[nf], acc[mf][nf], 0, 0, 0);
    }
    __syncthreads();
  }
  #pragma unroll
  for (int mf = 0; mf < 4; mf++) {
    int rb = r0 + wm * 64 + mf * 16 + (lk << 2);
    #pragma unroll
    for (int nf = 0; nf < 2; nf++) {
      int col = n0 + wn * 32 + nf * 16 + lrow;
      #pragma unroll
      for (int j = 0; j < 4; j++) {
        int p = rb + j;
        if (p < r1) {
          atomicAdd(&out[(size_t)tok_s[p] * H_DIM + col], wt_s[p] * acc[mf][nf][j]);
        }
      }
    }
  }
}

// ================= fallback (round-2 fp32-staging path) =================
__global__ __launch_bounds__(256) void moe_gemm1_fb(
    const float* __restrict__ hidden, const float* __restrict__ Wg,
    const float* __restrict__ Wu, const int* __restrict__ tok_s,
    const int* __restrict__ tile_e, const int* __restrict__ tile_r0,
    const int* __restrict__ tile_r1, const int* __restrict__ ntiles,
    short* __restrict__ act) {
  int bt = blockIdx.x;
  if (bt >= *ntiles) return;
  int e = tile_e[bt], r0 = tile_r0[bt], r1 = tile_r1[bt];
  int n0 = blockIdx.y * 64;
  const float* wg = Wg + (size_t)e * ((size_t)H_DIM * I_DIM);
  const float* wu = Wu + (size_t)e * ((size_t)H_DIM * I_DIM);
  __shared__ short As[BM * 32];
  __shared__ short Bg[64 * 32];
  __shared__ short Bu[64 * 32];
  int tid = threadIdx.x;
  int ar = tid >> 1, ah = tid & 1;
  int ap = r0 + ar; if (ap > NPAIR - 1) ap = NPAIR - 1;
  int atok = tok_s[ap];
  const float* asrc = hidden + (size_t)atok * H_DIM + ah * 16;
  int asw = swz32(ar);
  s16x8* aw0 = (s16x8*)&As[ar * 32 + (((ah * 2 + 0) ^ asw) << 3)];
  s16x8* aw1 = (s16x8*)&As[ar * 32 + (((ah * 2 + 1) ^ asw) << 3)];
  int bn = tid & 63, bkg = tid >> 6;
  const float* bg0 = wg + (size_t)(bkg * 8) * I_DIM + n0 + bn;
  const float* bu0 = wu + (size_t)(bkg * 8) * I_DIM + n0 + bn;
  int bso = bn * 32 + ((bkg ^ swz32(bn)) << 3);
  s16x8* bwg = (s16x8*)&Bg[bso];
  s16x8* bwu = (s16x8*)&Bu[bso];
  int lane = tid & 63, wv = tid >> 6;
  int wm = wv >> 1, wn = wv & 1;
  int lrow = lane & 15, lk = lane >> 4;
  f32x4 accg[4][2], accu[4][2];
  #pragma unroll
  for (int i = 0; i < 4; i++)
    #pragma unroll
    for (int j = 0; j < 2; j++) { accg[i][j] = 0; accu[i][j] = 0; }
  for (int k0 = 0; k0 < H_DIM; k0 += 32) {
    const float4* a = (const float4*)(asrc + k0);
    float4 f0 = a[0], f1 = a[1], f2 = a[2], f3 = a[3];
    float vgv[8], vuv[8];
    const float* pg = bg0 + (size_t)k0 * I_DIM;
    const float* pu = bu0 + (size_t)k0 * I_DIM;
    #pragma unroll
    for (int j = 0; j < 8; j++) { vgv[j] = pg[(size_t)j * I_DIM]; vuv[j] = pu[(size_t)j * I_DIM]; }
    __syncthreads();
    s16x8 p0, p1, qg, qu;
    p0[0]=f2bf(f0.x); p0[1]=f2bf(f0.y); p0[2]=f2bf(f0.z); p0[3]=f2bf(f0.w);
    p0[4]=f2bf(f1.x); p0[5]=f2bf(f1.y); p0[6]=f2bf(f1.z); p0[7]=f2bf(f1.w);
    p1[0]=f2bf(f2.x); p1[1]=f2bf(f2.y); p1[2]=f2bf(f2.z); p1[3]=f2bf(f2.w);
    p1[4]=f2bf(f3.x); p1[5]=f2bf(f3.y); p1[6]=f2bf(f3.z); p1[7]=f2bf(f3.w);
    #pragma unroll
    for (int j = 0; j < 8; j++) { qg[j] = f2bf(vgv[j]); qu[j] = f2bf(vuv[j]); }
    *aw0 = p0; *aw1 = p1; *bwg = qg; *bwu = qu;
    __syncthreads();
    s16x8 af[4], bfg[2], bfu[2];
    #pragma unroll
    for (int mf = 0; mf < 4; mf++) {
      int rr = wm * 64 + mf * 16 + lrow;
      af[mf] = *(const s16x8*)&As[rr * 32 + ((lk ^ swz32(rr)) << 3)];
    }
    #pragma unroll
    for (int nf = 0; nf < 2; nf++) {
      int rn = wn * 32 + nf * 16 + lrow;
      int ob = rn * 32 + ((lk ^ swz32(rn)) << 3);
      bfg[nf] = *(const s16x8*)&Bg[ob];
      bfu[nf] = *(const s16x8*)&Bu[ob];
    }
    #pragma unroll
    for (int mf = 0; mf < 4; mf++)
      #pragma unroll
      for (int nf = 0; nf < 2; nf++) {
        accg[mf][nf] = __builtin_amdgcn_mfma_f32_16x16x32_bf16(af[mf], bfg[nf], accg[mf][nf], 0, 0, 0);
        accu[mf][nf] = __builtin_amdgcn_mfma_f32_16x16x32_bf16(af[mf], bfu[nf], accu[mf][nf], 0, 0, 0);
      }
  }
  #pragma unroll
  for (int mf = 0; mf < 4; mf++) {
    int rb = r0 + wm * 64 + mf * 16 + (lk << 2);
    #pragma unroll
    for (int nf = 0; nf < 2; nf++) {
      int col = n0 + wn * 32 + nf * 16 + lrow;
      #pragma unroll
      for (int j = 0; j < 4; j++) {
        int p = rb + j;
        if (p < r1) {
          float g = accg[mf][nf][j], u = accu[mf][nf][j];
          float s = g / (1.f + __expf(-g)) * u;
          act[p * I_DIM + col] = f2bf(s);
        }
      }
    }
  }
}

__global__ __launch_bounds__(256) void moe_gemm2_fb(
    const short* __restrict__ act, const float* __restrict__ Wd,
    const int* __restrict__ tok_s, const float* __restrict__ wt_s,
    const int* __restrict__ tile_e, const int* __restrict__ tile_r0,
    const int* __restrict__ tile_r1, const int* __restrict__ ntiles,
    float* __restrict__ out) {
  int bt = blockIdx.x;
  if (bt >= *ntiles) return;
  int e = tile_e[bt], r0 = tile_r0[bt], r1 = tile_r1[bt];
  int n0 = blockIdx.y * 64;
  const float* wd = Wd + (size_t)e * ((size_t)I_DIM * H_DIM);
  __shared__ short As[BM * 32];
  __shared__ short Bd[64 * 32];
  int tid = threadIdx.x;
  int ar = tid >> 1, ah = tid & 1;
  int ap = r0 + ar; if (ap > NPAIR - 1) ap = NPAIR - 1;
  const short* asrc = act + (size_t)ap * I_DIM + ah * 16;
  int asw = swz32(ar);
  s16x8* aw0 = (s16x8*)&As[ar * 32 + (((ah * 2 + 0) ^ asw) << 3)];
  s16x8* aw1 = (s16x8*)&As[ar * 32 + (((ah * 2 + 1) ^ asw) << 3)];
  int bn = tid & 63, bkg = tid >> 6;
  const float* bd0 = wd + (size_t)(bkg * 8) * H_DIM + n0 + bn;
  s16x8* bwd = (s16x8*)&Bd[bn * 32 + ((bkg ^ swz32(bn)) << 3)];
  int lane = tid & 63, wv = tid >> 6;
  int wm = wv >> 1, wn = wv & 1;
  int lrow = lane & 15, lk = lane >> 4;
  f32x4 acc[4][2];
  #pragma unroll
  for (int i = 0; i < 4; i++)
    #pragma unroll
    for (int j = 0; j < 2; j++) acc[i][j] = 0;
  for (int k0 = 0; k0 < I_DIM; k0 += 32) {
    const s16x8* a = (const s16x8*)(asrc + k0);
    s16x8 v0 = a[0], v1 = a[1];
    float vd[8];
    const float* pd = bd0 + (size_t)k0 * H_DIM;
    #pragma unroll
    for (int j = 0; j < 8; j++) vd[j] = pd[(size_t)j * H_DIM];
    __syncthreads();
    s16x8 qd;
    #pragma unroll
    for (int j = 0; j < 8; j++) qd[j] = f2bf(vd[j]);
    *aw0 = v0; *aw1 = v1; *bwd = qd;
    __syncthreads();
    s16x8 af[4], bf[2];
    #pragma unroll
    for (int mf = 0; mf < 4; mf++) {
      int rr = wm * 64 + mf * 16 + lrow;
      af[mf] = *(const s16x8*)&As[rr * 32 + ((lk ^ swz32(rr)) << 3)];
    }
    #pragma unroll
    for (int nf = 0; nf < 2; nf++) {
      int rn = wn * 32 + nf * 16 + lrow;
      bf[nf] = *(const s16x8*)&Bd[rn * 32 + ((lk ^ swz32(rn)) << 3)];
    }
    #pragma unroll
    for (int mf = 0; mf < 4; mf++)
      #pragma unroll
      for (int nf = 0; nf < 2; nf++)
        acc[mf][nf] = __builtin_amdgcn_mfma_f32_16x16x32_bf16(af[mf], bf[nf], acc[mf][nf], 0, 0, 0);
  }
  #pragma unroll
  for (int mf = 0; mf < 4; mf++) {
    int rb = r0 + wm * 64 + mf * 16 + (lk << 2);
    #pragma unroll
    for (int nf = 0; nf < 2; nf++) {
      int col = n0 + wn * 32 + nf * 16 + lrow;
      #pragma unroll
      for (int j = 0; j < 4; j++) {
        int p = rb + j;
        if (p < r1) {
          atomicAdd(&out[(size_t)tok_s[p] * H_DIM + col], wt_s[p] * acc[mf][nf][j]);
        }
      }
    }
  }
}

extern "C" void kernel_launch(void* const* d_in, const int* in_sizes, int n_in,
                              void* d_out, int out_size, void* d_ws, size_t ws_size,
                              hipStream_t stream) {
  const float* hidden = (const float*)d_in[0];
  const int*   idx    = (const int*)d_in[1];
  const float* wts    = (const float*)d_in[2];
  const float* Wg     = (const float*)d_in[3];
  const float* Wu     = (const float*)d_in[4];
  const float* Wd     = (const float*)d_in[5];
  float* out = (float*)d_out;

  char* ws = (char*)d_ws;
  int*   tok_s   = (int*)(ws);
  float* wt_s    = (float*)(ws + 32768);
  int*   tile_e  = (int*)(ws + 65536);
  int*   tile_r0 = (int*)(ws + 66048);
  int*   tile_r1 = (int*)(ws + 66560);
  int*   ntiles  = (int*)(ws + 67072);

  const size_t OFF_HB  = 1ull << 20;                  // 16,777,216 B
  const size_t OFF_WGT = OFF_HB  + 16777216ull;       // 46,137,344 B each
  const size_t OFF_WUT = OFF_WGT + 46137344ull;
  const size_t OFF_WDT = OFF_WUT + 46137344ull;
  const size_t OFF_ACT = OFF_WDT + 46137344ull;
  const size_t REQ     = OFF_ACT + 23068672ull;       // ~171 MB

  moe_build<<<1, 256, 0, stream>>>(idx, wts, tok_s, wt_s, tile_e, tile_r0, tile_r1, ntiles);
  hipMemsetAsync(d_out, 0, (size_t)T_TOK * H_DIM * sizeof(float), stream);

  if (ws_size >= REQ) {
    short* hb  = (short*)(ws + OFF_HB);
    short* wgt = (short*)(ws + OFF_WGT);
    short* wut = (short*)(ws + OFF_WUT);
    short* wdt = (short*)(ws + OFF_WDT);
    short* act = (short*)(ws + OFF_ACT);
    conv_hidden<<<2048, 256, 0, stream>>>(hidden, hb);
    transpose_w<<<dim3(I_DIM / 64, H_DIM / 64, E_NUM), 256, 0, stream>>>(Wg, wgt, H_DIM, I_DIM);
    transpose_w<<<dim3(I_DIM / 64, H_DIM / 64, E_NUM), 256, 0, stream>>>(Wu, wut, H_DIM, I_DIM);
    transpose_w<<<dim3(H_DIM / 64, I_DIM / 64, E_NUM), 256, 0, stream>>>(Wd, wdt, I_DIM, H_DIM);
    moe_gemm1<<<dim3(72, I_DIM / 64), 256, 0, stream>>>(hb, wgt, wut, tok_s,
        tile_e, tile_r0, tile_r1, ntiles, act);
    moe_gemm2<<<dim3(72, H_DIM / 64), 256, 0, stream>>>(act, wdt, tok_s, wt_s,
        tile_e, tile_r0, tile_r1, ntiles, out);
  } else {
    short* act = (short*)(ws + 131072);
    moe_gemm1_fb<<<dim3(72, I_DIM / 64), 256, 0, stream>>>(hidden, Wg, Wu, tok_s,
        tile_e, tile_r0, tile_r1, ntiles, act);
    moe_gemm2_fb<<<dim3(72, H_DIM / 64), 256, 0, stream>>>(act, Wd, tok_s, wt_s,
        tile_e, tile_r0, tile_r1, ntiles, out);
  }
}

// Round 4
// 423.157 us; speedup vs baseline: 1.3049x; 1.0521x over previous
//
#include <hip/hip_runtime.h>

#define T_TOK 4096
#define H_DIM 2048
#define I_DIM 1408
#define E_NUM 8
#define NPAIR 8192
#define BM 128
#define BK 64

typedef float f32x4 __attribute__((ext_vector_type(4)));
typedef short s16x8 __attribute__((ext_vector_type(8)));

static __device__ __forceinline__ short f2bf(float f) {
  union { float f; unsigned u; } c; c.f = f;
  unsigned r = c.u + 0x7FFFu + ((c.u >> 16) & 1u);
  return (short)(r >> 16);
}

// global -> LDS direct, 16B per lane. LDS dest = wave-uniform base + lane*16.
#define GLD16(g, l) __builtin_amdgcn_global_load_lds( \
    (const __attribute__((address_space(1))) void*)(g), \
    (__attribute__((address_space(3))) void*)(l), 16, 0, 0)

// ---------------- pair sort + tile descriptors ----------------
__global__ __launch_bounds__(256) void moe_build(
    const int* __restrict__ idx, const float* __restrict__ wts,
    int* __restrict__ tok_s, float* __restrict__ wt_s,
    int* __restrict__ tile_e, int* __restrict__ tile_r0,
    int* __restrict__ tile_r1, int* __restrict__ ntiles) {
  __shared__ int cnt[E_NUM], cur[E_NUM];
  int tid = threadIdx.x;
  if (tid < E_NUM) cnt[tid] = 0;
  __syncthreads();
  for (int p = tid; p < NPAIR; p += 256) atomicAdd(&cnt[idx[p] & 7], 1);
  __syncthreads();
  if (tid == 0) {
    int o = 0, nt = 0;
    for (int e = 0; e < E_NUM; e++) {
      cur[e] = o;
      int c = cnt[e];
      for (int m0 = 0; m0 < c; m0 += BM) {
        tile_e[nt] = e;
        tile_r0[nt] = o + m0;
        tile_r1[nt] = o + ((m0 + BM < c) ? (m0 + BM) : c);
        nt++;
      }
      o += c;
    }
    *ntiles = nt;
  }
  __syncthreads();
  for (int p = tid; p < NPAIR; p += 256) {
    int e = idx[p] & 7;
    int pos = atomicAdd(&cur[e], 1);
    tok_s[pos] = p >> 1;
    wt_s[pos]  = wts[p];
  }
}

// ---------------- prepass: hidden fp32 -> bf16 ----------------
__global__ __launch_bounds__(256) void conv_hidden(
    const float* __restrict__ in, short* __restrict__ out) {
  size_t i = ((size_t)blockIdx.x * 256 + threadIdx.x) * 16;
  const f32x4* s = (const f32x4*)(in + i);
  f32x4 a = s[0], b = s[1], c = s[2], d = s[3];
  s16x8 v0, v1;
  v0[0]=f2bf(a[0]); v0[1]=f2bf(a[1]); v0[2]=f2bf(a[2]); v0[3]=f2bf(a[3]);
  v0[4]=f2bf(b[0]); v0[5]=f2bf(b[1]); v0[6]=f2bf(b[2]); v0[7]=f2bf(b[3]);
  v1[0]=f2bf(c[0]); v1[1]=f2bf(c[1]); v1[2]=f2bf(c[2]); v1[3]=f2bf(c[3]);
  v1[4]=f2bf(d[0]); v1[5]=f2bf(d[1]); v1[6]=f2bf(d[2]); v1[7]=f2bf(d[3]);
  *(s16x8*)(out + i) = v0;
  *(s16x8*)(out + i + 8) = v1;
}

// ---------------- prepass: [E][R][C] fp32 -> [E][C][R] bf16 ----------------
__global__ __launch_bounds__(256) void transpose_w(
    const float* __restrict__ in, short* __restrict__ out, int R, int C) {
  __shared__ short t[64][72];
  const float* src = in + (size_t)blockIdx.z * ((size_t)R * C);
  short* dst = out + (size_t)blockIdx.z * ((size_t)R * C);
  int r0 = blockIdx.y * 64, c0 = blockIdx.x * 64;
  int tid = threadIdx.x;
  int ir = tid >> 2, ic = (tid & 3) * 16;
  const f32x4* s = (const f32x4*)(src + (size_t)(r0 + ir) * C + c0 + ic);
  f32x4 a = s[0], b = s[1], c = s[2], d = s[3];
  short* w = &t[ir][ic];
  w[0]=f2bf(a[0]);  w[1]=f2bf(a[1]);  w[2]=f2bf(a[2]);  w[3]=f2bf(a[3]);
  w[4]=f2bf(b[0]);  w[5]=f2bf(b[1]);  w[6]=f2bf(b[2]);  w[7]=f2bf(b[3]);
  w[8]=f2bf(c[0]);  w[9]=f2bf(c[1]);  w[10]=f2bf(c[2]); w[11]=f2bf(c[3]);
  w[12]=f2bf(d[0]); w[13]=f2bf(d[1]); w[14]=f2bf(d[2]); w[15]=f2bf(d[3]);
  __syncthreads();
  int oc = tid >> 2, os = (tid & 3) * 16;
  s16x8 v0, v1;
  #pragma unroll
  for (int j = 0; j < 8; j++) { v0[j] = t[os + j][oc]; v1[j] = t[os + 8 + j][oc]; }
  short* o = dst + (size_t)(c0 + oc) * R + r0 + os;
  *(s16x8*)o = v0;
  *(s16x8*)(o + 8) = v1;
}

// ---------------- GEMM1: act = silu(X@Wg) * (X@Wu), all bf16 ----------------
// Tile 128(M) x 128(N) x 64(K). 4 waves in 2x2; each wave 64x64 per matrix.
__global__ __launch_bounds__(256, 2) void moe_gemm1(
    const short* __restrict__ hb, const short* __restrict__ Wgt,
    const short* __restrict__ Wut, const int* __restrict__ tok_s,
    const int* __restrict__ tile_e, const int* __restrict__ tile_r0,
    const int* __restrict__ tile_r1, const int* __restrict__ ntiles,
    short* __restrict__ act) {
  __shared__ short As[BM * BK];
  __shared__ short Bg[128 * BK];
  __shared__ short Bu[128 * BK];
  int bt = blockIdx.x;
  if (bt >= *ntiles) return;
  int e = tile_e[bt], r0 = tile_r0[bt], r1 = tile_r1[bt];
  int n0 = blockIdx.y * 128;
  const short* wg = Wgt + (size_t)e * ((size_t)H_DIM * I_DIM);
  const short* wu = Wut + (size_t)e * ((size_t)H_DIM * I_DIM);

  int tid = threadIdx.x, lane = tid & 63, wv = tid >> 6;
  int l3 = lane >> 3;
  int k8 = (((lane & 7) ^ l3) << 3);   // inverse-swizzled source k-chunk

  const short* a_src[4]; short* a_dst[4];
  const short* g_src[4]; short* g_dst[4];
  const short* u_src[4]; short* u_dst[4];
  #pragma unroll
  for (int s = 0; s < 4; s++) {
    int row = wv * 32 + s * 8 + l3;
    int p = r0 + row; if (p > NPAIR - 1) p = NPAIR - 1;
    a_src[s] = hb + (size_t)tok_s[p] * H_DIM + k8;
    a_dst[s] = As + (wv * 32 + s * 8) * BK;
    g_src[s] = wg + (size_t)(n0 + row) * H_DIM + k8;
    u_src[s] = wu + (size_t)(n0 + row) * H_DIM + k8;
    g_dst[s] = Bg + (wv * 32 + s * 8) * BK;
    u_dst[s] = Bu + (wv * 32 + s * 8) * BK;
  }

  int wm = wv >> 1, wn = wv & 1;
  int lrow = lane & 15, lk = lane >> 4;

  f32x4 accg[4][4], accu[4][4];
  #pragma unroll
  for (int i = 0; i < 4; i++)
    #pragma unroll
    for (int j = 0; j < 4; j++) { accg[i][j] = 0; accu[i][j] = 0; }

  for (int k0 = 0; k0 < H_DIM; k0 += BK) {
    #pragma unroll
    for (int s = 0; s < 4; s++) GLD16(a_src[s] + k0, a_dst[s]);
    #pragma unroll
    for (int s = 0; s < 4; s++) GLD16(g_src[s] + k0, g_dst[s]);
    #pragma unroll
    for (int s = 0; s < 4; s++) GLD16(u_src[s] + k0, u_dst[s]);
    __syncthreads();
    #pragma unroll
    for (int ks = 0; ks < 2; ks++) {
      s16x8 af[4], bgf[4], buf_[4];
      #pragma unroll
      for (int mf = 0; mf < 4; mf++) {
        int rr = wm * 64 + mf * 16 + lrow;
        af[mf] = *(const s16x8*)&As[rr * BK + ((((ks << 2) + lk) ^ (rr & 7)) << 3)];
      }
      #pragma unroll
      for (int nf = 0; nf < 4; nf++) {
        int rn = wn * 64 + nf * 16 + lrow;
        int o = rn * BK + ((((ks << 2) + lk) ^ (rn & 7)) << 3);
        bgf[nf] = *(const s16x8*)&Bg[o];
        buf_[nf] = *(const s16x8*)&Bu[o];
      }
      #pragma unroll
      for (int mf = 0; mf < 4; mf++)
        #pragma unroll
        for (int nf = 0; nf < 4; nf++) {
          accg[mf][nf] = __builtin_amdgcn_mfma_f32_16x16x32_bf16(af[mf], bgf[nf], accg[mf][nf], 0, 0, 0);
          accu[mf][nf] = __builtin_amdgcn_mfma_f32_16x16x32_bf16(af[mf], buf_[nf], accu[mf][nf], 0, 0, 0);
        }
    }
    __syncthreads();
  }
  #pragma unroll
  for (int mf = 0; mf < 4; mf++) {
    int rb = r0 + wm * 64 + mf * 16 + (lk << 2);
    #pragma unroll
    for (int nf = 0; nf < 4; nf++) {
      int col = n0 + wn * 64 + nf * 16 + lrow;
      #pragma unroll
      for (int j = 0; j < 4; j++) {
        int p = rb + j;
        if (p < r1) {
          float g = accg[mf][nf][j], u = accu[mf][nf][j];
          float s = g / (1.f + __expf(-g)) * u;
          act[p * I_DIM + col] = f2bf(s);
        }
      }
    }
  }
}

// ---------------- GEMM2: out[tok] += wt * (act @ Wd), bf16 MFMA ----------------
__global__ __launch_bounds__(256, 2) void moe_gemm2(
    const short* __restrict__ act, const short* __restrict__ Wdt,
    const int* __restrict__ tok_s, const float* __restrict__ wt_s,
    const int* __restrict__ tile_e, const int* __restrict__ tile_r0,
    const int* __restrict__ tile_r1, const int* __restrict__ ntiles,
    float* __restrict__ out) {
  __shared__ short As[BM * BK];
  __shared__ short Bd[128 * BK];
  int bt = blockIdx.x;
  if (bt >= *ntiles) return;
  int e = tile_e[bt], r0 = tile_r0[bt], r1 = tile_r1[bt];
  int n0 = blockIdx.y * 128;
  const short* wd = Wdt + (size_t)e * ((size_t)H_DIM * I_DIM);

  int tid = threadIdx.x, lane = tid & 63, wv = tid >> 6;
  int l3 = lane >> 3;
  int k8 = (((lane & 7) ^ l3) << 3);

  const short* a_src[4]; short* a_dst[4];
  const short* b_src[4]; short* b_dst[4];
  #pragma unroll
  for (int s = 0; s < 4; s++) {
    int row = wv * 32 + s * 8 + l3;
    int p = r0 + row; if (p > NPAIR - 1) p = NPAIR - 1;
    a_src[s] = act + (size_t)p * I_DIM + k8;
    a_dst[s] = As + (wv * 32 + s * 8) * BK;
    b_src[s] = wd + (size_t)(n0 + row) * I_DIM + k8;
    b_dst[s] = Bd + (wv * 32 + s * 8) * BK;
  }

  int wm = wv >> 1, wn = wv & 1;
  int lrow = lane & 15, lk = lane >> 4;

  f32x4 acc[4][4];
  #pragma unroll
  for (int i = 0; i < 4; i++)
    #pragma unroll
    for (int j = 0; j < 4; j++) acc[i][j] = 0;

  for (int k0 = 0; k0 < I_DIM; k0 += BK) {
    #pragma unroll
    for (int s = 0; s < 4; s++) GLD16(a_src[s] + k0, a_dst[s]);
    #pragma unroll
    for (int s = 0; s < 4; s++) GLD16(b_src[s] + k0, b_dst[s]);
    __syncthreads();
    #pragma unroll
    for (int ks = 0; ks < 2; ks++) {
      s16x8 af[4], bf[4];
      #pragma unroll
      for (int mf = 0; mf < 4; mf++) {
        int rr = wm * 64 + mf * 16 + lrow;
        af[mf] = *(const s16x8*)&As[rr * BK + ((((ks << 2) + lk) ^ (rr & 7)) << 3)];
      }
      #pragma unroll
      for (int nf = 0; nf < 4; nf++) {
        int rn = wn * 64 + nf * 16 + lrow;
        bf[nf] = *(const s16x8*)&Bd[rn * BK + ((((ks << 2) + lk) ^ (rn & 7)) << 3)];
      }
      #pragma unroll
      for (int mf = 0; mf < 4; mf++)
        #pragma unroll
        for (int nf = 0; nf < 4; nf++)
          acc[mf][nf] = __builtin_amdgcn_mfma_f32_16x16x32_bf16(af[mf], bf[nf], acc[mf][nf], 0, 0, 0);
    }
    __syncthreads();
  }
  #pragma unroll
  for (int mf = 0; mf < 4; mf++) {
    int rb = r0 + wm * 64 + mf * 16 + (lk << 2);
    #pragma unroll
    for (int nf = 0; nf < 4; nf++) {
      int col = n0 + wn * 64 + nf * 16 + lrow;
      #pragma unroll
      for (int j = 0; j < 4; j++) {
        int p = rb + j;
        if (p < r1) {
          atomicAdd(&out[(size_t)tok_s[p] * H_DIM + col], wt_s[p] * acc[mf][nf][j]);
        }
      }
    }
  }
}

extern "C" void kernel_launch(void* const* d_in, const int* in_sizes, int n_in,
                              void* d_out, int out_size, void* d_ws, size_t ws_size,
                              hipStream_t stream) {
  const float* hidden = (const float*)d_in[0];
  const int*   idx    = (const int*)d_in[1];
  const float* wts    = (const float*)d_in[2];
  const float* Wg     = (const float*)d_in[3];
  const float* Wu     = (const float*)d_in[4];
  const float* Wd     = (const float*)d_in[5];
  float* out = (float*)d_out;

  char* ws = (char*)d_ws;
  int*   tok_s   = (int*)(ws);
  float* wt_s    = (float*)(ws + 32768);
  int*   tile_e  = (int*)(ws + 65536);
  int*   tile_r0 = (int*)(ws + 66048);
  int*   tile_r1 = (int*)(ws + 66560);
  int*   ntiles  = (int*)(ws + 67072);

  const size_t OFF_HB  = 1ull << 20;
  const size_t OFF_WGT = OFF_HB  + 16777216ull;
  const size_t OFF_WUT = OFF_WGT + 46137344ull;
  const size_t OFF_WDT = OFF_WUT + 46137344ull;
  const size_t OFF_ACT = OFF_WDT + 46137344ull;

  short* hb  = (short*)(ws + OFF_HB);
  short* wgt = (short*)(ws + OFF_WGT);
  short* wut = (short*)(ws + OFF_WUT);
  short* wdt = (short*)(ws + OFF_WDT);
  short* act = (short*)(ws + OFF_ACT);

  moe_build<<<1, 256, 0, stream>>>(idx, wts, tok_s, wt_s, tile_e, tile_r0, tile_r1, ntiles);
  hipMemsetAsync(d_out, 0, (size_t)T_TOK * H_DIM * sizeof(float), stream);
  conv_hidden<<<2048, 256, 0, stream>>>(hidden, hb);
  transpose_w<<<dim3(I_DIM / 64, H_DIM / 64, E_NUM), 256, 0, stream>>>(Wg, wgt, H_DIM, I_DIM);
  transpose_w<<<dim3(I_DIM / 64, H_DIM / 64, E_NUM), 256, 0, stream>>>(Wu, wut, H_DIM, I_DIM);
  transpose_w<<<dim3(H_DIM / 64, I_DIM / 64, E_NUM), 256, 0, stream>>>(Wd, wdt, I_DIM, H_DIM);
  moe_gemm1<<<dim3(72, I_DIM / 128), 256, 0, stream>>>(hb, wgt, wut, tok_s,
      tile_e, tile_r0, tile_r1, ntiles, act);
  moe_gemm2<<<dim3(72, H_DIM / 128), 256, 0, stream>>>(act, wdt, tok_s, wt_s,
      tile_e, tile_r0, tile_r1, ntiles, out);
}

// Round 5
// 360.948 us; speedup vs baseline: 1.5298x; 1.1723x over previous
//
#include <hip/hip_runtime.h>

#define T_TOK 4096
#define H_DIM 2048
#define I_DIM 1408
#define E_NUM 8
#define NPAIR 8192
#define BM 128
#define BK 64

typedef float f32x4 __attribute__((ext_vector_type(4)));
typedef short s16x8 __attribute__((ext_vector_type(8)));

static __device__ __forceinline__ short f2bf(float f) {
  union { float f; unsigned u; } c; c.f = f;
  unsigned r = c.u + 0x7FFFu + ((c.u >> 16) & 1u);
  return (short)(r >> 16);
}

// global -> LDS direct, 16B per lane. LDS dest = wave-uniform base + lane*16.
#define GLD16(g, l) __builtin_amdgcn_global_load_lds( \
    (const __attribute__((address_space(1))) void*)(g), \
    (__attribute__((address_space(3))) void*)(l), 16, 0, 0)

// ---------------- pair sort + tile descriptors ----------------
__global__ __launch_bounds__(256) void moe_build(
    const int* __restrict__ idx, const float* __restrict__ wts,
    int* __restrict__ tok_s, float* __restrict__ wt_s, int* __restrict__ inv,
    int* __restrict__ tile_e, int* __restrict__ tile_r0,
    int* __restrict__ tile_r1, int* __restrict__ ntiles) {
  __shared__ int cnt[E_NUM], cur[E_NUM];
  int tid = threadIdx.x;
  if (tid < E_NUM) cnt[tid] = 0;
  __syncthreads();
  for (int p = tid; p < NPAIR; p += 256) atomicAdd(&cnt[idx[p] & 7], 1);
  __syncthreads();
  if (tid == 0) {
    int o = 0, nt = 0;
    for (int e = 0; e < E_NUM; e++) {
      cur[e] = o;
      int c = cnt[e];
      for (int m0 = 0; m0 < c; m0 += BM) {
        tile_e[nt] = e;
        tile_r0[nt] = o + m0;
        tile_r1[nt] = o + ((m0 + BM < c) ? (m0 + BM) : c);
        nt++;
      }
      o += c;
    }
    *ntiles = nt;
  }
  __syncthreads();
  for (int p = tid; p < NPAIR; p += 256) {
    int e = idx[p] & 7;
    int pos = atomicAdd(&cur[e], 1);
    tok_s[pos] = p >> 1;
    wt_s[pos]  = wts[p];
    inv[p]     = pos;
  }
}

// ---------------- prepass: hidden fp32 -> bf16 ----------------
__global__ __launch_bounds__(256) void conv_hidden(
    const float* __restrict__ in, short* __restrict__ out) {
  size_t i = ((size_t)blockIdx.x * 256 + threadIdx.x) * 16;
  const f32x4* s = (const f32x4*)(in + i);
  f32x4 a = s[0], b = s[1], c = s[2], d = s[3];
  s16x8 v0, v1;
  v0[0]=f2bf(a[0]); v0[1]=f2bf(a[1]); v0[2]=f2bf(a[2]); v0[3]=f2bf(a[3]);
  v0[4]=f2bf(b[0]); v0[5]=f2bf(b[1]); v0[6]=f2bf(b[2]); v0[7]=f2bf(b[3]);
  v1[0]=f2bf(c[0]); v1[1]=f2bf(c[1]); v1[2]=f2bf(c[2]); v1[3]=f2bf(c[3]);
  v1[4]=f2bf(d[0]); v1[5]=f2bf(d[1]); v1[6]=f2bf(d[2]); v1[7]=f2bf(d[3]);
  *(s16x8*)(out + i) = v0;
  *(s16x8*)(out + i + 8) = v1;
}

// ---------------- prepass: [E][R][C] fp32 -> [E][C][R] bf16 ----------------
__global__ __launch_bounds__(256) void transpose_w(
    const float* __restrict__ in, short* __restrict__ out, int R, int C) {
  __shared__ short t[64][72];
  const float* src = in + (size_t)blockIdx.z * ((size_t)R * C);
  short* dst = out + (size_t)blockIdx.z * ((size_t)R * C);
  int r0 = blockIdx.y * 64, c0 = blockIdx.x * 64;
  int tid = threadIdx.x;
  int ir = tid >> 2, ic = (tid & 3) * 16;
  const f32x4* s = (const f32x4*)(src + (size_t)(r0 + ir) * C + c0 + ic);
  f32x4 a = s[0], b = s[1], c = s[2], d = s[3];
  short* w = &t[ir][ic];
  w[0]=f2bf(a[0]);  w[1]=f2bf(a[1]);  w[2]=f2bf(a[2]);  w[3]=f2bf(a[3]);
  w[4]=f2bf(b[0]);  w[5]=f2bf(b[1]);  w[6]=f2bf(b[2]);  w[7]=f2bf(b[3]);
  w[8]=f2bf(c[0]);  w[9]=f2bf(c[1]);  w[10]=f2bf(c[2]); w[11]=f2bf(c[3]);
  w[12]=f2bf(d[0]); w[13]=f2bf(d[1]); w[14]=f2bf(d[2]); w[15]=f2bf(d[3]);
  __syncthreads();
  int oc = tid >> 2, os = (tid & 3) * 16;
  s16x8 v0, v1;
  #pragma unroll
  for (int j = 0; j < 8; j++) { v0[j] = t[os + j][oc]; v1[j] = t[os + 8 + j][oc]; }
  short* o = dst + (size_t)(c0 + oc) * R + r0 + os;
  *(s16x8*)o = v0;
  *(s16x8*)(o + 8) = v1;
}

// ---------------- GEMM1: act = silu(X@Wg) * (X@Wu), all bf16 ----------------
// Tile 128(M) x 128(N) x 64(K). 4 waves in 2x2; each wave 64x64 per matrix.
__global__ __launch_bounds__(256, 2) void moe_gemm1(
    const short* __restrict__ hb, const short* __restrict__ Wgt,
    const short* __restrict__ Wut, const int* __restrict__ tok_s,
    const int* __restrict__ tile_e, const int* __restrict__ tile_r0,
    const int* __restrict__ tile_r1, const int* __restrict__ ntiles,
    short* __restrict__ act) {
  __shared__ short As[BM * BK];
  __shared__ short Bg[128 * BK];
  __shared__ short Bu[128 * BK];
  int bt = blockIdx.x;
  if (bt >= *ntiles) return;
  int e = tile_e[bt], r0 = tile_r0[bt], r1 = tile_r1[bt];
  int n0 = blockIdx.y * 128;
  const short* wg = Wgt + (size_t)e * ((size_t)H_DIM * I_DIM);
  const short* wu = Wut + (size_t)e * ((size_t)H_DIM * I_DIM);

  int tid = threadIdx.x, lane = tid & 63, wv = tid >> 6;
  int l3 = lane >> 3;
  int k8 = (((lane & 7) ^ l3) << 3);   // inverse-swizzled source k-chunk

  const short* a_src[4]; short* a_dst[4];
  const short* g_src[4]; short* g_dst[4];
  const short* u_src[4]; short* u_dst[4];
  #pragma unroll
  for (int s = 0; s < 4; s++) {
    int row = wv * 32 + s * 8 + l3;
    int p = r0 + row; if (p > NPAIR - 1) p = NPAIR - 1;
    a_src[s] = hb + (size_t)tok_s[p] * H_DIM + k8;
    a_dst[s] = As + (wv * 32 + s * 8) * BK;
    g_src[s] = wg + (size_t)(n0 + row) * H_DIM + k8;
    u_src[s] = wu + (size_t)(n0 + row) * H_DIM + k8;
    g_dst[s] = Bg + (wv * 32 + s * 8) * BK;
    u_dst[s] = Bu + (wv * 32 + s * 8) * BK;
  }

  int wm = wv >> 1, wn = wv & 1;
  int lrow = lane & 15, lk = lane >> 4;

  f32x4 accg[4][4], accu[4][4];
  #pragma unroll
  for (int i = 0; i < 4; i++)
    #pragma unroll
    for (int j = 0; j < 4; j++) { accg[i][j] = 0; accu[i][j] = 0; }

  for (int k0 = 0; k0 < H_DIM; k0 += BK) {
    #pragma unroll
    for (int s = 0; s < 4; s++) GLD16(a_src[s] + k0, a_dst[s]);
    #pragma unroll
    for (int s = 0; s < 4; s++) GLD16(g_src[s] + k0, g_dst[s]);
    #pragma unroll
    for (int s = 0; s < 4; s++) GLD16(u_src[s] + k0, u_dst[s]);
    __syncthreads();
    #pragma unroll
    for (int ks = 0; ks < 2; ks++) {
      s16x8 af[4], bgf[4], buf_[4];
      #pragma unroll
      for (int mf = 0; mf < 4; mf++) {
        int rr = wm * 64 + mf * 16 + lrow;
        af[mf] = *(const s16x8*)&As[rr * BK + ((((ks << 2) + lk) ^ (rr & 7)) << 3)];
      }
      #pragma unroll
      for (int nf = 0; nf < 4; nf++) {
        int rn = wn * 64 + nf * 16 + lrow;
        int o = rn * BK + ((((ks << 2) + lk) ^ (rn & 7)) << 3);
        bgf[nf] = *(const s16x8*)&Bg[o];
        buf_[nf] = *(const s16x8*)&Bu[o];
      }
      #pragma unroll
      for (int mf = 0; mf < 4; mf++)
        #pragma unroll
        for (int nf = 0; nf < 4; nf++) {
          accg[mf][nf] = __builtin_amdgcn_mfma_f32_16x16x32_bf16(af[mf], bgf[nf], accg[mf][nf], 0, 0, 0);
          accu[mf][nf] = __builtin_amdgcn_mfma_f32_16x16x32_bf16(af[mf], buf_[nf], accu[mf][nf], 0, 0, 0);
        }
    }
    __syncthreads();
  }
  #pragma unroll
  for (int mf = 0; mf < 4; mf++) {
    int rb = r0 + wm * 64 + mf * 16 + (lk << 2);
    #pragma unroll
    for (int nf = 0; nf < 4; nf++) {
      int col = n0 + wn * 64 + nf * 16 + lrow;
      #pragma unroll
      for (int j = 0; j < 4; j++) {
        int p = rb + j;
        if (p < r1) {
          float g = accg[mf][nf][j], u = accu[mf][nf][j];
          float s = g / (1.f + __expf(-g)) * u;
          act[p * I_DIM + col] = f2bf(s);
        }
      }
    }
  }
}

// ---------------- GEMM2: y[pos] = act[pos] @ Wd, plain fp32 stores ----------------
__global__ __launch_bounds__(256, 2) void moe_gemm2(
    const short* __restrict__ act, const short* __restrict__ Wdt,
    const int* __restrict__ tile_e, const int* __restrict__ tile_r0,
    const int* __restrict__ tile_r1, const int* __restrict__ ntiles,
    float* __restrict__ y) {
  __shared__ short As[BM * BK];
  __shared__ short Bd[128 * BK];
  int bt = blockIdx.x;
  if (bt >= *ntiles) return;
  int e = tile_e[bt], r0 = tile_r0[bt], r1 = tile_r1[bt];
  int n0 = blockIdx.y * 128;
  const short* wd = Wdt + (size_t)e * ((size_t)H_DIM * I_DIM);

  int tid = threadIdx.x, lane = tid & 63, wv = tid >> 6;
  int l3 = lane >> 3;
  int k8 = (((lane & 7) ^ l3) << 3);

  const short* a_src[4]; short* a_dst[4];
  const short* b_src[4]; short* b_dst[4];
  #pragma unroll
  for (int s = 0; s < 4; s++) {
    int row = wv * 32 + s * 8 + l3;
    int p = r0 + row; if (p > NPAIR - 1) p = NPAIR - 1;
    a_src[s] = act + (size_t)p * I_DIM + k8;
    a_dst[s] = As + (wv * 32 + s * 8) * BK;
    b_src[s] = wd + (size_t)(n0 + row) * I_DIM + k8;
    b_dst[s] = Bd + (wv * 32 + s * 8) * BK;
  }

  int wm = wv >> 1, wn = wv & 1;
  int lrow = lane & 15, lk = lane >> 4;

  f32x4 acc[4][4];
  #pragma unroll
  for (int i = 0; i < 4; i++)
    #pragma unroll
    for (int j = 0; j < 4; j++) acc[i][j] = 0;

  for (int k0 = 0; k0 < I_DIM; k0 += BK) {
    #pragma unroll
    for (int s = 0; s < 4; s++) GLD16(a_src[s] + k0, a_dst[s]);
    #pragma unroll
    for (int s = 0; s < 4; s++) GLD16(b_src[s] + k0, b_dst[s]);
    __syncthreads();
    #pragma unroll
    for (int ks = 0; ks < 2; ks++) {
      s16x8 af[4], bf[4];
      #pragma unroll
      for (int mf = 0; mf < 4; mf++) {
        int rr = wm * 64 + mf * 16 + lrow;
        af[mf] = *(const s16x8*)&As[rr * BK + ((((ks << 2) + lk) ^ (rr & 7)) << 3)];
      }
      #pragma unroll
      for (int nf = 0; nf < 4; nf++) {
        int rn = wn * 64 + nf * 16 + lrow;
        bf[nf] = *(const s16x8*)&Bd[rn * BK + ((((ks << 2) + lk) ^ (rn & 7)) << 3)];
      }
      #pragma unroll
      for (int mf = 0; mf < 4; mf++)
        #pragma unroll
        for (int nf = 0; nf < 4; nf++)
          acc[mf][nf] = __builtin_amdgcn_mfma_f32_16x16x32_bf16(af[mf], bf[nf], acc[mf][nf], 0, 0, 0);
    }
    __syncthreads();
  }
  #pragma unroll
  for (int mf = 0; mf < 4; mf++) {
    int rb = r0 + wm * 64 + mf * 16 + (lk << 2);
    #pragma unroll
    for (int nf = 0; nf < 4; nf++) {
      int col = n0 + wn * 64 + nf * 16 + lrow;
      #pragma unroll
      for (int j = 0; j < 4; j++) {
        int p = rb + j;
        if (p < r1) {
          y[(size_t)p * H_DIM + col] = acc[mf][nf][j];
        }
      }
    }
  }
}

// ---------------- combine: out[t] = w0*y[inv[2t]] + w1*y[inv[2t+1]] ----------------
__global__ __launch_bounds__(256) void moe_combine(
    const float* __restrict__ y, const int* __restrict__ inv,
    const float* __restrict__ wt_s, float* __restrict__ out) {
  int t = blockIdx.x;
  int p0 = inv[2 * t], p1 = inv[2 * t + 1];
  float w0 = wt_s[p0], w1 = wt_s[p1];
  const f32x4* y0 = (const f32x4*)(y + (size_t)p0 * H_DIM);
  const f32x4* y1 = (const f32x4*)(y + (size_t)p1 * H_DIM);
  f32x4* o = (f32x4*)(out + (size_t)t * H_DIM);
  int i = threadIdx.x;
  f32x4 a0 = y0[i], b0 = y1[i];
  f32x4 a1 = y0[i + 256], b1 = y1[i + 256];
  o[i] = w0 * a0 + w1 * b0;
  o[i + 256] = w0 * a1 + w1 * b1;
}

extern "C" void kernel_launch(void* const* d_in, const int* in_sizes, int n_in,
                              void* d_out, int out_size, void* d_ws, size_t ws_size,
                              hipStream_t stream) {
  const float* hidden = (const float*)d_in[0];
  const int*   idx    = (const int*)d_in[1];
  const float* wts    = (const float*)d_in[2];
  const float* Wg     = (const float*)d_in[3];
  const float* Wu     = (const float*)d_in[4];
  const float* Wd     = (const float*)d_in[5];
  float* out = (float*)d_out;

  char* ws = (char*)d_ws;
  int*   tok_s   = (int*)(ws);
  float* wt_s    = (float*)(ws + 32768);
  int*   tile_e  = (int*)(ws + 65536);
  int*   tile_r0 = (int*)(ws + 66048);
  int*   tile_r1 = (int*)(ws + 66560);
  int*   ntiles  = (int*)(ws + 67072);
  int*   inv     = (int*)(ws + 131072);   // 32 KB

  const size_t OFF_HB  = 1ull << 20;
  const size_t OFF_WGT = OFF_HB  + 16777216ull;
  const size_t OFF_WUT = OFF_WGT + 46137344ull;
  const size_t OFF_WDT = OFF_WUT + 46137344ull;
  const size_t OFF_ACT = OFF_WDT + 46137344ull;

  short* hb  = (short*)(ws + OFF_HB);
  short* wgt = (short*)(ws + OFF_WGT);
  short* wut = (short*)(ws + OFF_WUT);
  short* wdt = (short*)(ws + OFF_WDT);
  short* act = (short*)(ws + OFF_ACT);
  // y aliases wgt+wut (92 MB region, y needs 67 MB): wgt/wut are dead after
  // moe_gemm1, and y is only written by moe_gemm2 (same stream, ordered).
  float* y   = (float*)(ws + OFF_WGT);

  moe_build<<<1, 256, 0, stream>>>(idx, wts, tok_s, wt_s, inv, tile_e, tile_r0, tile_r1, ntiles);
  conv_hidden<<<2048, 256, 0, stream>>>(hidden, hb);
  transpose_w<<<dim3(I_DIM / 64, H_DIM / 64, E_NUM), 256, 0, stream>>>(Wg, wgt, H_DIM, I_DIM);
  transpose_w<<<dim3(I_DIM / 64, H_DIM / 64, E_NUM), 256, 0, stream>>>(Wu, wut, H_DIM, I_DIM);
  transpose_w<<<dim3(H_DIM / 64, I_DIM / 64, E_NUM), 256, 0, stream>>>(Wd, wdt, I_DIM, H_DIM);
  moe_gemm1<<<dim3(72, I_DIM / 128), 256, 0, stream>>>(hb, wgt, wut, tok_s,
      tile_e, tile_r0, tile_r1, ntiles, act);
  moe_gemm2<<<dim3(72, H_DIM / 128), 256, 0, stream>>>(act, wdt,
      tile_e, tile_r0, tile_r1, ntiles, y);
  moe_combine<<<T_TOK, 256, 0, stream>>>(y, inv, wt_s, out);
}